// Round 1
// baseline (450.821 us; speedup 1.0000x reference)
//
#include <hip/hip_runtime.h>
#include <hip/hip_bf16.h>

typedef __attribute__((ext_vector_type(4))) float f32x4;
typedef __attribute__((ext_vector_type(8))) short short8;

// sizes: B=2048, S=4, L=16, K=8, E=256, V=128
#define NB 2048

__device__ __forceinline__ float bf2f(ushort u) {
    union { unsigned int u; float f; } x; x.u = ((unsigned int)u) << 16; return x.f;
}
__device__ __forceinline__ ushort f2bf(float f) {
    union { float f; unsigned int u; } x; x.f = f;
    unsigned int u = x.u;
    unsigned int r = (u + 0x7fffu + ((u >> 16) & 1u)) >> 16;  // RNE
    return (ushort)r;
}

// ---------------------------------------------------------------------------
// k_prep: grid 257.  Blocks 0..255: repack conv_weight (E,E,3,3) f32 ->
// Wg bf16 [o][k], k = t*256+i.  Block 256: masks = softmax(action_table @
// action_W^T + b) rows, and zero loss/acc slots of d_out.
// ---------------------------------------------------------------------------
__global__ __launch_bounds__(256) void k_prep(
    const float* __restrict__ conv_w, const float* __restrict__ a_table,
    const float* __restrict__ a_W, const float* __restrict__ a_b,
    float* __restrict__ masks, ushort* __restrict__ Wg,
    float* __restrict__ out_head)
{
    __shared__ float ao[4][9];
    const int bid = blockIdx.x, tid = threadIdx.x;
    if (bid == 256) {
        if (tid < 36) {
            const int a = tid / 9, t = tid % 9;
            float s = a_b[t];
            for (int c = 0; c < 32; c++) s += a_table[a * 32 + c] * a_W[t * 32 + c];
            ao[a][t] = s;
        }
        __syncthreads();
        if (tid < 4) {
            float mx = -1e30f;
            for (int t = 0; t < 9; t++) mx = fmaxf(mx, ao[tid][t]);
            float e[9], z = 0.f;
            for (int t = 0; t < 9; t++) { e[t] = expf(ao[tid][t] - mx); z += e[t]; }
            for (int t = 0; t < 9; t++) masks[tid * 9 + t] = e[t] / z;
        }
        if (tid == 64) { out_head[0] = 0.f; out_head[1] = 0.f; }
    } else {
        const int o = bid;
        for (int q = 0; q < 9; q++) {                     // q == t
            const float v = conv_w[(o * 256 + tid) * 9 + q];  // conv_w[o][i=tid][t=q]
            Wg[o * 2304 + q * 256 + tid] = f2bf(v);
        }
    }
}

// ---------------------------------------------------------------------------
// k_emb: grid B*S = 8192 blocks, 256 thr (e).  emb[b][s][e] = sum_l gold[gs]
// ---------------------------------------------------------------------------
__global__ __launch_bounds__(256) void k_emb(
    const float* __restrict__ gold, const int* __restrict__ gs,
    float* __restrict__ emb)
{
    const int bs = blockIdx.x, e = threadIdx.x;
    const int* g = gs + bs * 16;
    float s = 0.f;
    #pragma unroll
    for (int l = 0; l < 16; l++) s += gold[g[l] * 256 + e];
    emb[bs * 256 + e] = s;
}

// ---------------------------------------------------------------------------
// k_lemb: grid B = 2048 blocks, 256 thr (e).
// l_emb[b][p][e] = sum_k (idx!=0 ? map_table[idx][e] : 0).  Writes f32 (for
// final logits) and bf16 (conv input, position-major [b][p][e]).
// ---------------------------------------------------------------------------
__global__ __launch_bounds__(256) void k_lemb(
    const float* __restrict__ mapt, const int* __restrict__ lms,
    float* __restrict__ lp32, ushort* __restrict__ c0)
{
    const int b = blockIdx.x, e = threadIdx.x;
    for (int p = 0; p < 16; p++) {
        const int* lm = lms + (b * 16 + p) * 8;
        float s = 0.f;
        #pragma unroll
        for (int k = 0; k < 8; k++) {
            const int idx = lm[k];
            if (idx) s += mapt[idx * 256 + e];
        }
        lp32[(b * 16 + p) * 256 + e] = s;
        c0[(b * 16 + p) * 256 + e] = f2bf(s);
    }
}

// ---------------------------------------------------------------------------
// k_conv: one masked-conv step as GEMM.  Block = 4 samples (N=64), BM=256,
// BK=32, 4 waves.  W (bf16 [o][t*256+i]) shared by all blocks (L2-resident).
// X tile built on the fly from cur [b][p][i] with shift/zero-pad and mask.
// mfma_f32_16x16x32_bf16; A row = lane&15, k=(lane>>4)*8+j; B col = lane&15.
// ---------------------------------------------------------------------------
__global__ __launch_bounds__(256) void k_conv(
    const ushort* __restrict__ cur, const ushort* __restrict__ Wg,
    const float* __restrict__ masks, const int* __restrict__ actions,
    const int j, ushort* __restrict__ outp)
{
    __shared__ __align__(16) ushort Wlds[256][48];  // 32 used + pad (bank spread)
    __shared__ __align__(16) ushort Xlds[64][48];
    __shared__ float mlds[4][9];
    const int tid = threadIdx.x;
    const int b0 = blockIdx.x * 4;
    if (tid < 36) {
        const int s = tid / 9, t = tid % 9;
        mlds[s][t] = masks[actions[(b0 + s) * 3 + j] * 9 + t];
    }
    const int wid = tid >> 6, lane = tid & 63;
    const int l15 = lane & 15, l4 = lane >> 4;
    // X-build mapping: thread -> (col, k-quarter)
    const int xc = tid >> 2, xq = tid & 3;
    const int xs = xc >> 4, xp = xc & 15;
    const int xh = xp >> 2, xw = xp & 3;
    const ushort* curb = cur + (size_t)(b0 + xs) * 16 * 256;
    const ushort* wrow = Wg + tid * 2304;

    f32x4 acc[4][4];
    #pragma unroll
    for (int a = 0; a < 4; a++)
        #pragma unroll
        for (int b = 0; b < 4; b++) acc[a][b] = (f32x4){0.f, 0.f, 0.f, 0.f};

    uint4 xv, w0, w1, w2, w3;
    auto load_tile = [&](int k0) {
        const int t = k0 >> 8, i0 = k0 & 255;
        const int hh = xh + t / 3 - 1, ww = xw + t % 3 - 1;
        xv = make_uint4(0u, 0u, 0u, 0u);
        if (hh >= 0 && hh < 4 && ww >= 0 && ww < 4) {
            const ushort* src = curb + ((hh << 2) + ww) * 256 + i0 + xq * 8;
            uint4 v = *(const uint4*)src;
            const float mm = mlds[xs][t];
            const ushort* vi = (const ushort*)&v;
            ushort* vo = (ushort*)&xv;
            #pragma unroll
            for (int e = 0; e < 8; e++) vo[e] = f2bf(bf2f(vi[e]) * mm);
        }
        w0 = *(const uint4*)(wrow + k0);
        w1 = *(const uint4*)(wrow + k0 + 8);
        w2 = *(const uint4*)(wrow + k0 + 16);
        w3 = *(const uint4*)(wrow + k0 + 24);
    };

    __syncthreads();          // mlds visible
    load_tile(0);
    for (int k0 = 0; k0 < 2304; k0 += 32) {
        __syncthreads();      // previous iter's frag reads done
        *(uint4*)&Xlds[xc][xq * 8] = xv;
        *(uint4*)&Wlds[tid][0]  = w0;
        *(uint4*)&Wlds[tid][8]  = w1;
        *(uint4*)&Wlds[tid][16] = w2;
        *(uint4*)&Wlds[tid][24] = w3;
        __syncthreads();      // tile visible
        if (k0 + 32 < 2304) load_tile(k0 + 32);  // prefetch overlaps MFMA
        short8 af[4], bfr[4];
        #pragma unroll
        for (int mt = 0; mt < 4; mt++)
            af[mt] = *(const short8*)&Wlds[wid * 64 + mt * 16 + l15][l4 * 8];
        #pragma unroll
        for (int nt = 0; nt < 4; nt++)
            bfr[nt] = *(const short8*)&Xlds[nt * 16 + l15][l4 * 8];
        #pragma unroll
        for (int mt = 0; mt < 4; mt++)
            #pragma unroll
            for (int nt = 0; nt < 4; nt++)
                acc[mt][nt] = __builtin_amdgcn_mfma_f32_16x16x32_bf16(
                    af[mt], bfr[nt], acc[mt][nt], 0, 0, 0);
    }
    // epilogue: C/D frag col=lane&15 (=p), row=(lane>>4)*4+r (=o)
    #pragma unroll
    for (int nt = 0; nt < 4; nt++) {
        const size_t bb = (size_t)(b0 + nt);
        #pragma unroll
        for (int mt = 0; mt < 4; mt++) {
            const int ob = wid * 64 + mt * 16 + l4 * 4;
            ushort o4[4];
            #pragma unroll
            for (int r = 0; r < 4; r++) o4[r] = f2bf(acc[mt][nt][r]);
            *(uint2*)&outp[(bb * 16 + l15) * 256 + ob] = *(const uint2*)o4;
        }
    }
}

// ---------------------------------------------------------------------------
// k_final: grid B = 2048 blocks.  logits[b][p] = sum_s sum_e lm_s[b][p][e] *
// emb[b][s*256+e]  (s=0 in f32, s>=1 bf16).  Then prob = softmax(logits),
// logp = log_softmax(prob), loss/acc via atomics.
// ---------------------------------------------------------------------------
__global__ __launch_bounds__(256) void k_final(
    const float* __restrict__ lp32, const ushort* __restrict__ c1,
    const ushort* __restrict__ c2, const ushort* __restrict__ c3,
    const float* __restrict__ emb, const int* __restrict__ y,
    float* __restrict__ d_out)
{
    __shared__ float red[256];
    __shared__ float lg[16];
    const int b = blockIdx.x, tid = threadIdx.x;
    const int p = tid >> 4, g = tid & 15;
    const float* embb = emb + b * 1024;
    float a = 0.f;
    {
        const float* row = lp32 + (size_t)(b * 16 + p) * 256;
        #pragma unroll 4
        for (int q = 0; q < 16; q++) { const int e = g + q * 16; a += row[e] * embb[e]; }
    }
    const ushort* cs[3] = { c1, c2, c3 };
    for (int s = 1; s < 4; s++) {
        const ushort* row = cs[s - 1] + (size_t)(b * 16 + p) * 256;
        const float* eb = embb + s * 256;
        #pragma unroll 4
        for (int q = 0; q < 16; q++) { const int e = g + q * 16; a += bf2f(row[e]) * eb[e]; }
    }
    red[tid] = a;
    __syncthreads();
    for (int st = 8; st >= 1; st >>= 1) {
        if (g < st) red[tid] += red[tid + st];
        __syncthreads();
    }
    if (g == 0) lg[p] = red[tid];
    __syncthreads();
    if (tid == 0) {
        float mx = -1e30f;
        for (int q = 0; q < 16; q++) mx = fmaxf(mx, lg[q]);
        float ex[16], z = 0.f;
        for (int q = 0; q < 16; q++) { ex[q] = expf(lg[q] - mx); z += ex[q]; }
        float prob[16];
        for (int q = 0; q < 16; q++) {
            prob[q] = ex[q] / z;
            d_out[2 + b * 16 + q] = prob[q];
        }
        int am = 0; float bv = prob[0];
        for (int q = 1; q < 16; q++) if (prob[q] > bv) { bv = prob[q]; am = q; }
        const int yt = y[b * 2] * 4 + y[b * 2 + 1];
        float z2 = 0.f;
        for (int q = 0; q < 16; q++) z2 += expf(prob[q]);
        const float logp = prob[yt] - logf(z2);
        atomicAdd(&d_out[0], -logp * (1.0f / 2048.0f));
        atomicAdd(&d_out[1], (am == yt) ? (1.0f / 2048.0f) : 0.0f);
    }
}

// ---------------------------------------------------------------------------
extern "C" void kernel_launch(void* const* d_in, const int* in_sizes, int n_in,
                              void* d_out, int out_size, void* d_ws, size_t ws_size,
                              hipStream_t stream) {
    const float* gold_table = (const float*)d_in[0];   // (11,256)
    const float* map_table  = (const float*)d_in[1];   // (128,256)
    const float* conv_w     = (const float*)d_in[2];   // (256,256,3,3)
    const float* a_table    = (const float*)d_in[3];   // (4,32)
    const float* a_W        = (const float*)d_in[4];   // (9,32)
    const float* a_b        = (const float*)d_in[5];   // (9,)
    const int*   gs         = (const int*)d_in[6];     // (2048,4,16)
    const int*   actions    = (const int*)d_in[7];     // (2048,3)
    const int*   lms        = (const int*)d_in[8];     // (2048,4,4,8)
    const int*   y          = (const int*)d_in[9];     // (2048,2)
    float* out = (float*)d_out;

    char* ws = (char*)d_ws;
    float*  masks = (float*)(ws + 0);                         // 144 B
    ushort* Wg    = (ushort*)(ws + 256);                      // 1,179,648 B
    float*  emb   = (float*)(ws + 1179904);                   // 8,388,608 B
    float*  lp32  = (float*)(ws + 9568512);                   // 33,554,432 B
    ushort* c0    = (ushort*)(ws + 43122944);                 // 16,777,216 B
    ushort* c1    = (ushort*)(ws + 59900160);
    ushort* c2    = (ushort*)(ws + 76677376);
    ushort* c3    = (ushort*)(ws + 93454592);                 // end ~110.2 MB
    (void)in_sizes; (void)n_in; (void)out_size; (void)ws_size;

    k_prep<<<257, 256, 0, stream>>>(conv_w, a_table, a_W, a_b, masks, Wg, out);
    k_emb<<<8192, 256, 0, stream>>>(gold_table, gs, emb);
    k_lemb<<<2048, 256, 0, stream>>>(map_table, lms, lp32, c0);
    k_conv<<<512, 256, 0, stream>>>(c0, Wg, masks, actions, 0, c1);
    k_conv<<<512, 256, 0, stream>>>(c1, Wg, masks, actions, 1, c2);
    k_conv<<<512, 256, 0, stream>>>(c2, Wg, masks, actions, 2, c3);
    k_final<<<2048, 256, 0, stream>>>(lp32, c1, c2, c3, emb, y, out);
}